// Round 6
// baseline (20698.311 us; speedup 1.0000x reference)
//
#include <hip/hip_runtime.h>
#include <stdint.h>
#include <stddef.h>

#define SEQ 2048
#define FD  256

typedef float f32x4 __attribute__((ext_vector_type(4)));
typedef short bf16x8 __attribute__((ext_vector_type(8)));

// ---------------- workspace layout (bytes) ----------------
// Small state first so the DIRECT fallback works with ~1.1 MiB of scratch.
// hbuf: 2 parity * 4 groups * 8 WG-blocks * (16 batch * 32 col) bf16 = 64 KiB.
// Per-WG block = 1024B, cache-line-disjoint across WGs (XCD L2 writeback safety).
static constexpr size_t OFF_USW  = 0;                                  // U concat, B-frag bf16: 512 KiB
static constexpr size_t OFF_VSW  = OFF_USW + (size_t)256 * 1024 * 2;   // V concat, B-frag bf16: 512 KiB
static constexpr size_t OFF_BCAT = OFF_VSW + (size_t)256 * 1024 * 2;   // 4 KiB fp32 bias concat
static constexpr size_t OFF_HBUF = OFF_BCAT + 4096;                    // 64 KiB (was 32 KiB: the R4 bug)
static constexpr size_t OFF_FLG  = OFF_HBUF + 65536;                   // 4 counters @ 128B stride
static constexpr size_t OFF_ASW  = OFF_FLG + 4096;                     // x in MFMA-A-frag bf16: 64 MiB
static constexpr size_t SZ_ASW   = (size_t)131072 * 256 * 2;
static constexpr size_t WS_SMALL = OFF_ASW;
static constexpr size_t WS_NEED  = OFF_ASW + SZ_ASW;

__device__ __forceinline__ uint16_t f2bf(float f) {
  uint32_t u = __builtin_bit_cast(uint32_t, f);
  return (uint16_t)((u + 0x7FFFu + ((u >> 16) & 1u)) >> 16);   // RNE
}

__device__ __forceinline__ bf16x8 pack_bf8(f32x4 a0, f32x4 a1) {
  union { uint16_t h[8]; bf16x8 v; } u;
  #pragma unroll
  for (int j = 0; j < 4; j++) { u.h[j] = f2bf(a0[j]); u.h[4 + j] = f2bf(a1[j]); }
  return u.v;
}

// x (B,S,F) fp32  ->  A_sw: for m = t*64+b, frag fid=(m>>4)*8+kk, lane=(m&15)|(((k>>3)&3)<<4), elem j=k&7
__global__ void k_prep_x(const float* __restrict__ x, uint4* __restrict__ asw) {
  int id   = blockIdx.x * 256 + threadIdx.x;   // 4,194,304 threads, write-contiguous mapping
  int lane = id & 63, fid = id >> 6;
  int kk   = fid & 7, mblk = fid >> 3;         // mblk = t*4 + g
  int m    = mblk * 16 + (lane & 15);
  int ko   = kk * 4 + (lane >> 4);             // k-octet index 0..31
  int b    = m & 63, t = m >> 6;
  const float* sp = x + ((size_t)b * SEQ + t) * FD + ko * 8;
  f32x4 a0 = *(const f32x4*)sp;
  f32x4 a1 = *(const f32x4*)(sp + 4);
  union { bf16x8 v; uint4 q; } u;
  u.v = pack_bf8(a0, a1);
  asw[id] = u.q;
}

// U/V (4 gates, each (256,256) fp32) -> B-frag swizzled bf16; plus bias concat; plus flag init
__global__ void k_prep_w(const float* __restrict__ U0, const float* __restrict__ U1,
                         const float* __restrict__ U2, const float* __restrict__ U3,
                         const float* __restrict__ V0, const float* __restrict__ V1,
                         const float* __restrict__ V2, const float* __restrict__ V3,
                         const float* __restrict__ b0, const float* __restrict__ b1,
                         const float* __restrict__ b2, const float* __restrict__ b3,
                         uint8_t* __restrict__ ws) {
  int id = blockIdx.x * 256 + threadIdx.x;
  if (id < 65536) {
    bool isV = id >= 32768;
    int cid  = id & 32767;
    int lane = cid & 63, fid = cid >> 6;
    int kk = fid & 7, nf = fid >> 3;
    int col = nf * 16 + (lane & 15);           // global z-column 0..1023
    int gate = col >> 8, c = col & 255;
    int k0 = kk * 32 + (lane >> 4) * 8;
    const float* s0 = isV ? V0 : U0;
    const float* s1 = isV ? V1 : U1;
    const float* s2 = isV ? V2 : U2;
    const float* s3 = isV ? V3 : U3;
    const float* src = (gate == 0) ? s0 : (gate == 1) ? s1 : (gate == 2) ? s2 : s3;
    union { uint16_t h[8]; uint4 q; } u;
    #pragma unroll
    for (int j = 0; j < 8; j++) u.h[j] = f2bf(src[(size_t)(k0 + j) * 256 + c]);
    ((uint4*)(ws + (isV ? OFF_VSW : OFF_USW)))[cid] = u.q;
  } else if (id < 66560) {
    int i = id - 65536;                        // 0..1023
    const float* bp = (i < 256) ? b0 : (i < 512) ? b1 : (i < 768) ? b2 : b3;
    ((float*)(ws + OFF_BCAT))[i] = bp[i & 255];
  } else if (id < 66564) {
    ((uint32_t*)(ws + OFF_FLG))[(id - 66560) * 32] = 0u;   // 128B stride
  }
}

#define MFMA16(a, b, c) __builtin_amdgcn_mfma_f32_16x16x32_bf16((a), (b), (c), 0, 0, 0)

// One recurrence step. XN = array to prefetch (frags for step T+1); AXC = bias + x_T*U (ready);
// AXN = computed here for T+1 (overlapped with exchange).
// hbuf element index: [par]*16384 + g*4096 + w*512 + bb*32 + col32  (per-WG 1KiB blocks)
// read at (batch=l15, hcol=kk*32+lhi*8+j): owner w'=kk, col32=lhi*8+j -> contiguous 16B.
#define STEP(T, XN, AXC, AXN) do {                                                        \
  f32x4 acc_;                                                                             \
  if ((T) > 0) {                                                                          \
    const uint16_t* hb_ = hbuf + (size_t)(((T)-1) & 1) * 16384 + g * 4096 + l15 * 32 + lhi * 8; \
    bf16x8 hr_[8];                                                                        \
    _Pragma("unroll")                                                                     \
    for (int kk = 0; kk < 8; kk++) hr_[kk] = *(const bf16x8*)(hb_ + kk * 512);            \
    f32x4 p0_ = {0.f,0.f,0.f,0.f}, p1_ = {0.f,0.f,0.f,0.f};                               \
    _Pragma("unroll")                                                                     \
    for (int kk = 0; kk < 8; kk += 2) {                                                   \
      p0_ = MFMA16(hr_[kk],     vf[kk],     p0_);                                         \
      p1_ = MFMA16(hr_[kk + 1], vf[kk + 1], p1_);                                         \
    }                                                                                     \
    acc_ = AXC + p0_ + p1_;                                                               \
  } else { acc_ = AXC; }                                                                  \
  *(f32x4*)&z_lds[zw_idx] = acc_;                                                         \
  __syncthreads();                                                                        \
  if ((T) + 1 < SEQ) {                                                                    \
    if constexpr (DIRECT) {                                                               \
      const float* xp_ = xg + ((size_t)(g * 16 + l15) * SEQ + ((T) + 1)) * FD + lhi * 8;  \
      _Pragma("unroll")                                                                   \
      for (int kk = 0; kk < 8; kk++) {                                                    \
        f32x4 a0_ = *(const f32x4*)(xp_ + kk * 32);                                       \
        f32x4 a1_ = *(const f32x4*)(xp_ + kk * 32 + 4);                                   \
        XN[kk] = pack_bf8(a0_, a1_);                                                      \
      }                                                                                   \
    } else {                                                                              \
      const uint4* xp_ = asw + ((size_t)((T) + 1) * 4 + (size_t)g) * 512;                 \
      _Pragma("unroll")                                                                   \
      for (int kk = 0; kk < 8; kk++) XN[kk] = *(const bf16x8*)(xp_ + kk * 64 + lane);     \
    }                                                                                     \
  }                                                                                       \
  float zi_ = z_lds[        c32 * 20 + bb];                                               \
  float zf_ = z_lds[ 640 +  c32 * 20 + bb];                                               \
  float zg_ = z_lds[1280 +  c32 * 20 + bb];                                               \
  float zo_ = z_lds[1920 +  c32 * 20 + bb];                                               \
  float ig_ = 1.f / (1.f + __expf(-zi_));                                                 \
  float fg_ = 1.f / (1.f + __expf(-zf_));                                                 \
  float gg_ = 1.f - 2.f / (__expf(2.f * zg_) + 1.f);                                      \
  float og_ = 1.f / (1.f + __expf(-zo_));                                                 \
  c_reg = fg_ * c_reg + ig_ * gg_;                                                        \
  float hh_ = og_ * (1.f - 2.f / (__expf(2.f * c_reg) + 1.f));                            \
  if ((T) + 1 < SEQ) {                                                                    \
    f32x4 q0_ = bias4, q1_ = {0.f,0.f,0.f,0.f};                                           \
    _Pragma("unroll")                                                                     \
    for (int kk = 0; kk < 8; kk += 2) {                                                   \
      q0_ = MFMA16(XN[kk],     uf[kk],     q0_);                                          \
      q1_ = MFMA16(XN[kk + 1], uf[kk + 1], q1_);                                          \
    }                                                                                     \
    AXN = q0_ + q1_;                                                                      \
    hbuf[(size_t)((T) & 1) * 16384 + g * 4096 + w * 512 + bb * 32 + c32] = f2bf(hh_);     \
    __threadfence();                                                                      \
    __syncthreads();                                                                      \
    if (tid == 0) {                                                                       \
      __hip_atomic_fetch_add(flag, 1u, __ATOMIC_RELEASE, __HIP_MEMORY_SCOPE_AGENT);       \
      uint32_t tgt_ = 8u * ((uint32_t)(T) + 1u);                                          \
      while (__hip_atomic_load(flag, __ATOMIC_RELAXED, __HIP_MEMORY_SCOPE_AGENT) < tgt_)  \
        __builtin_amdgcn_s_sleep(1);                                                      \
    }                                                                                     \
    __syncthreads();                                                                      \
    __builtin_amdgcn_fence(__ATOMIC_ACQUIRE, "agent");                                    \
  } else {                                                                                \
    out[(g * 16 + bb) * 256 + kcol]         = hh_;                                        \
    out[16384 + (g * 16 + bb) * 256 + kcol] = c_reg;                                      \
  }                                                                                       \
} while (0)

// 32 blocks x 512 threads. Group g = bid&3 (16 batch rows), WG w = bid>>2 owns 32 h-cols (128 z-cols).
template <int DIRECT>
__global__ __launch_bounds__(512, 2) void k_scan(uint8_t* __restrict__ ws, float* __restrict__ out,
                                                 const float* __restrict__ xg) {
  __shared__ float z_lds[2560];   // [gate4][col32][batch16 pad->20]

  const int tid  = threadIdx.x;
  const int bid  = blockIdx.x;
  const int g    = bid & 3, w = bid >> 2;
  const int lane = tid & 63, v = tid >> 6;
  const int l15  = lane & 15, lhi = lane >> 4;
  const int zbase = 256 * (v >> 1) + 32 * w + 16 * (v & 1);  // wave's 16 z-cols start
  const int nf    = zbase >> 4;

  const uint4*    asw  = (const uint4*)(ws + OFF_ASW);
  const uint4*    usw  = (const uint4*)(ws + OFF_USW);
  const uint4*    vsw  = (const uint4*)(ws + OFF_VSW);
  const float*    bcat = (const float*)(ws + OFF_BCAT);
  uint16_t*       hbuf = (uint16_t*)(ws + OFF_HBUF);
  uint32_t*       flag = (uint32_t*)(ws + OFF_FLG) + g * 32;

  // resident weight fragments: 64 VGPRs/lane
  bf16x8 uf[8], vf[8];
  #pragma unroll
  for (int kk = 0; kk < 8; kk++) {
    uf[kk] = *(const bf16x8*)(usw + (nf * 8 + kk) * 64 + lane);
    vf[kk] = *(const bf16x8*)(vsw + (nf * 8 + kk) * 64 + lane);
  }
  float bv = bcat[zbase + l15];
  f32x4 bias4 = {bv, bv, bv, bv};

  // gate-phase ownership: thread -> (batch bb, local col c32); h-col = 32w + c32
  const int bb = tid & 15, c32 = tid >> 4;
  const int kcol = 32 * w + c32;
  const int zw_idx = ((v >> 1) * 32 + 16 * (v & 1) + l15) * 20 + 4 * lhi;
  float c_reg = 0.0f;

  bf16x8 xa[8], xb[8];
  f32x4 ax0, ax1;

  // prologue: load x frags for t=0 and compute ax0 = bias + x_0*U
  {
    if constexpr (DIRECT) {
      const float* xp = xg + ((size_t)(g * 16 + l15) * SEQ + 0) * FD + lhi * 8;
      #pragma unroll
      for (int kk = 0; kk < 8; kk++) {
        f32x4 a0 = *(const f32x4*)(xp + kk * 32);
        f32x4 a1 = *(const f32x4*)(xp + kk * 32 + 4);
        xa[kk] = pack_bf8(a0, a1);
      }
    } else {
      const uint4* xp = asw + (size_t)g * 512;
      #pragma unroll
      for (int kk = 0; kk < 8; kk++) xa[kk] = *(const bf16x8*)(xp + kk * 64 + lane);
    }
    f32x4 q0 = bias4, q1 = {0.f,0.f,0.f,0.f};
    #pragma unroll
    for (int kk = 0; kk < 8; kk += 2) {
      q0 = MFMA16(xa[kk],     uf[kk],     q0);
      q1 = MFMA16(xa[kk + 1], uf[kk + 1], q1);
    }
    ax0 = q0 + q1;
  }

  for (int t = 0; t < SEQ; t += 2) {
    STEP(t,     xb, ax0, ax1);
    STEP(t + 1, xa, ax1, ax0);
  }
}

extern "C" void kernel_launch(void* const* d_in, const int* in_sizes, int n_in,
                              void* d_out, int out_size, void* d_ws, size_t ws_size,
                              hipStream_t stream) {
  if (ws_size < WS_SMALL) return;   // insufficient scratch -> visible fail, no crash
  const float* x  = (const float*)d_in[0];
  const float* Ui = (const float*)d_in[1];
  const float* Vi = (const float*)d_in[2];
  const float* bi = (const float*)d_in[3];
  const float* Uf = (const float*)d_in[4];
  const float* Vf = (const float*)d_in[5];
  const float* bf = (const float*)d_in[6];
  const float* Uc = (const float*)d_in[7];
  const float* Vc = (const float*)d_in[8];
  const float* bc = (const float*)d_in[9];
  const float* Uo = (const float*)d_in[10];
  const float* Vo = (const float*)d_in[11];
  const float* bo = (const float*)d_in[12];
  uint8_t* ws = (uint8_t*)d_ws;
  float* out  = (float*)d_out;

  k_prep_w<<<261, 256, 0, stream>>>(Ui, Uf, Uc, Uo, Vi, Vf, Vc, Vo, bi, bf, bc, bo, ws);
  if (ws_size >= WS_NEED) {
    k_prep_x<<<16384, 256, 0, stream>>>(x, (uint4*)(ws + OFF_ASW));
    k_scan<0><<<32, 512, 0, stream>>>(ws, out, x);
  } else {
    k_scan<1><<<32, 512, 0, stream>>>(ws, out, x);
  }
}